// Round 1
// baseline (102.454 us; speedup 1.0000x reference)
//
#include <hip/hip_runtime.h>

#define P_IDS 512
#define DIM 8
#define QMIN 0.01f
#define REP 10.0f

typedef unsigned long long ull;
typedef float f32x4 __attribute__((ext_vector_type(4)));
typedef short s16x8 __attribute__((ext_vector_type(8)));

// ---- bf16 helpers (RNE via bit trick; no __bf16 type dependence) ----
__device__ __forceinline__ unsigned int bf16_rne(float f) {
    unsigned int u = __float_as_uint(f);
    return (u + 0x7FFFu + ((u >> 16) & 1u)) >> 16;   // low 16 bits = bf16
}
__device__ __forceinline__ float bf16_to_f32(unsigned int h) {
    return __uint_as_float(h << 16);
}
// exact-split pack: v[d] ~= hi[d] + lo[d] (both bf16), packed 8x16b -> uint4
__device__ __forceinline__ void split_pack(const float* v, uint4& hiw, uint4& low) {
    unsigned int hb[8], lb[8];
#pragma unroll
    for (int d = 0; d < 8; ++d) {
        unsigned int h = bf16_rne(v[d]);
        float rem = v[d] - bf16_to_f32(h);
        hb[d] = h;
        lb[d] = bf16_rne(rem);
    }
    hiw = make_uint4(hb[0] | (hb[1] << 16), hb[2] | (hb[3] << 16),
                     hb[4] | (hb[5] << 16), hb[6] | (hb[7] << 16));
    low = make_uint4(lb[0] | (lb[1] << 16), lb[2] | (lb[3] << 16),
                     lb[4] | (lb[5] << 16), lb[6] | (lb[7] << 16));
}

// Stage A: q_i = arctanh(beta_i)^2 + QMIN; per-block segmented argmax into LDS
// (key = qbits<<32 | ~i -> order-preserving for q>0, min-index on ties).
__launch_bounds__(256)
__global__ void stageA_kernel(const float* __restrict__ beta,
                              const int* __restrict__ pid,
                              float* __restrict__ q_out,
                              ull* __restrict__ tables,
                              int n) {
    __shared__ ull s_keys[P_IDS];
    s_keys[threadIdx.x] = 0ULL;
    s_keys[threadIdx.x + 256] = 0ULL;
    __syncthreads();
    int i = blockIdx.x * 256 + threadIdx.x;
    if (i < n) {
        float b = beta[i];
        float at = 0.5f * logf((1.0f + b) / (1.0f - b));   // arctanh
        float qv = fmaf(at, at, QMIN);
        q_out[i] = qv;
        ull key = ((ull)__float_as_uint(qv) << 32) |
                  (ull)(unsigned int)(~(unsigned int)i);
        atomicMax(&s_keys[pid[i]], key);
    }
    __syncthreads();
    ull* dst = tables + (size_t)blockIdx.x * P_IDS;
    dst[threadIdx.x] = s_keys[threadIdx.x];
    dst[threadIdx.x + 256] = s_keys[threadIdx.x + 256];
}

// Stage B: one block per particle id; reduce partial keys, decode, gather
// x_alpha, precompute ||x_alpha||^2, and emit bf16 hi/lo split of x_alpha
// for the MFMA loss kernel. Block 0 zeroes the output accumulator.
__launch_bounds__(64)
__global__ void stageB_kernel(const ull* __restrict__ tables, int ntab,
                              const float* __restrict__ x,
                              float2* __restrict__ meta,
                              float* __restrict__ x_alpha,
                              uint4* __restrict__ gB,
                              float* __restrict__ out) {
    int p = blockIdx.x;
    ull k = 0ULL;
    for (int t = threadIdx.x; t < ntab; t += 64) {
        ull v = tables[(size_t)t * P_IDS + p];
        k = (v > k) ? v : k;
    }
#pragma unroll
    for (int off = 32; off > 0; off >>= 1) {
        ull o = __shfl_down(k, off, 64);
        k = (o > k) ? o : k;
    }
    if (threadIdx.x == 0) {
        bool valid = (k != 0ULL) && (p != 0);
        float qa = valid ? __uint_as_float((unsigned int)(k >> 32)) : 0.0f;
        int idx = valid ? (int)(~(unsigned int)(k & 0xFFFFFFFFull)) : 0;
        float4 a = ((const float4*)x)[idx * 2];
        float4 b = ((const float4*)x)[idx * 2 + 1];
        float xa2 = a.x * a.x;
        xa2 = fmaf(a.y, a.y, xa2); xa2 = fmaf(a.z, a.z, xa2); xa2 = fmaf(a.w, a.w, xa2);
        xa2 = fmaf(b.x, b.x, xa2); xa2 = fmaf(b.y, b.y, xa2); xa2 = fmaf(b.z, b.z, xa2);
        xa2 = fmaf(b.w, b.w, xa2);
        ((float4*)x_alpha)[p * 2] = a;
        ((float4*)x_alpha)[p * 2 + 1] = b;
        meta[p] = make_float2(qa, xa2);
        float xv[8] = {a.x, a.y, a.z, a.w, b.x, b.y, b.z, b.w};
        uint4 hiw, low; split_pack(xv, hiw, low);
        gB[p] = hiw;           // hi half
        gB[P_IDS + p] = low;   // lo half
        if (p == 0) out[0] = 0.0f;
    }
}

// Loss: block = 64 hits x all 512 particles. Each of 4 waves owns a 16-hit
// row tile; per 16-particle tile one mfma_f32_16x16x32_bf16 computes
// sq = ||xi||^2 + ||xa||^2 - 2 xi.xa directly (C seeded with the norm sums,
// A = exact bf16 hi/lo split of -2xi packed [hi,lo,hi,lo] over k-groups,
// B = split of xa packed [hi,hi,lo,lo] -> hi.hi+lo.hi+hi.lo+lo.lo).
// Hinge (dist<1) is rare: wave-vote skips the sqrt path on ~88% of tiles.
// Own-pair excluded via pid compare in the rare path; attractive term done
// exactly in fp32 per hit in the prologue.
__launch_bounds__(256)
__global__ void loss_kernel(const float* __restrict__ x,
                            const float* __restrict__ q,
                            const int* __restrict__ pid,
                            const float2* __restrict__ meta,
                            const float* __restrict__ x_alpha,
                            const uint4* __restrict__ gB,
                            float* __restrict__ out, int n) {
    __shared__ uint4  s_B[2 * P_IDS];      // 16 KB: hi[512] | lo[512]
    __shared__ float2 s_meta[P_IDS];       // 4 KB: (qa, xa2)
    __shared__ uint4  s_A[128];            // 2 KB: hi[64] | lo[64] of -2x
    __shared__ __align__(16) float s_xi2[64];
    __shared__ __align__(16) float s_qi[64];
    __shared__ __align__(16) int   s_pid[64];

    int tid = threadIdx.x;
    float partial = 0.0f;

    if (tid < 64) {
        int i = blockIdx.x * 64 + tid;
        bool act = i < n;
        int ii = act ? i : 0;
        float4 v0 = ((const float4*)x)[ii * 2];
        float4 v1 = ((const float4*)x)[ii * 2 + 1];
        float xv[8] = {v0.x, v0.y, v0.z, v0.w, v1.x, v1.y, v1.z, v1.w};
        float s = 0.0f;
#pragma unroll
        for (int d = 0; d < 8; ++d) s = fmaf(xv[d], xv[d], s);
        float qi = act ? q[ii] : 0.0f;   // qi=0 kills padded rows everywhere
        int   pd = act ? pid[ii] : 0;
        s_xi2[tid] = act ? s : 0.0f;
        s_qi[tid]  = qi;
        s_pid[tid] = pd;
        float m2[8];
#pragma unroll
        for (int d = 0; d < 8; ++d) m2[d] = act ? (-2.0f * xv[d]) : 0.0f;
        uint4 hiw, low; split_pack(m2, hiw, low);
        s_A[tid] = hiw; s_A[64 + tid] = low;
        // attractive own-pair term, exact fp32
        float2 mm = meta[pd];
        float4 a0 = ((const float4*)x_alpha)[pd * 2];
        float4 a1 = ((const float4*)x_alpha)[pd * 2 + 1];
        float dot = xv[0] * a0.x;
        dot = fmaf(xv[1], a0.y, dot); dot = fmaf(xv[2], a0.z, dot);
        dot = fmaf(xv[3], a0.w, dot); dot = fmaf(xv[4], a1.x, dot);
        dot = fmaf(xv[5], a1.y, dot); dot = fmaf(xv[6], a1.z, dot);
        dot = fmaf(xv[7], a1.w, dot);
        float sqe = fmaxf(fmaf(-2.0f, dot, s + mm.y), 0.0f);
        partial = qi * mm.x * sqe;
    }
    for (int k = tid; k < 2 * P_IDS; k += 256) s_B[k] = gB[k];
    for (int k = tid; k < P_IDS; k += 256) s_meta[k] = meta[k];
    __syncthreads();

    int lane = tid & 63;
    int wid  = tid >> 6;
    int grp  = lane >> 4;
    int col  = lane & 15;

    // A fragment: row = wid*16 + col; k-groups [hi,lo,hi,lo] -> sel = grp&1
    s16x8 av = *reinterpret_cast<const s16x8*>(
        &s_A[((grp & 1) << 6) + wid * 16 + col]);
    // accumulator rows for this lane: wid*16 + grp*4 + r  (m89-verified C map)
    int rbase = wid * 16 + (grp << 2);
    f32x4 xi2r = *reinterpret_cast<const f32x4*>(&s_xi2[rbase]);
    f32x4 qir  = *reinterpret_cast<const f32x4*>(&s_qi[rbase]);
    int4  pidr = *reinterpret_cast<const int4*>(&s_pid[rbase]);

    // B fragment base: k-groups [hi,hi,lo,lo] -> sel = grp>=2
    const uint4* bptr = &s_B[((grp >= 2) ? P_IDS : 0) + col];
    f32x4 rp = {0.0f, 0.0f, 0.0f, 0.0f};

#pragma unroll
    for (int jt = 0; jt < P_IDS / 16; ++jt) {
        s16x8 bv = *reinterpret_cast<const s16x8*>(&bptr[jt * 16]);
        float2 mm = s_meta[jt * 16 + col];
        f32x4 c;
        c[0] = xi2r[0] + mm.y; c[1] = xi2r[1] + mm.y;
        c[2] = xi2r[2] + mm.y; c[3] = xi2r[3] + mm.y;
        c = __builtin_amdgcn_mfma_f32_16x16x32_bf16(av, bv, c, 0, 0, 0);
        float mn = fminf(fminf(c[0], c[1]), fminf(c[2], c[3]));
        if (__any(mn < 1.0f)) {          // hinge active somewhere in tile
            int p = jt * 16 + col;
#pragma unroll
            for (int r = 0; r < 4; ++r) {
                float sq = fmaxf(c[r], 0.0f);
                float vr = fmaxf(1.0f - __builtin_amdgcn_sqrtf(sq), 0.0f);
                float w  = (pidr[r] == p) ? 0.0f : mm.x;  // exclude own pair
                rp[r] = fmaf(vr, w, rp[r]);
            }
        }
    }
    partial += REP * (qir[0] * rp[0] + qir[1] * rp[1] +
                      qir[2] * rp[2] + qir[3] * rp[3]);

#pragma unroll
    for (int off = 32; off > 0; off >>= 1)
        partial += __shfl_down(partial, off, 64);
    __shared__ float s_red[4];
    if ((tid & 63) == 0) s_red[tid >> 6] = partial;
    __syncthreads();
    if (tid == 0)
        atomicAdd(out, (s_red[0] + s_red[1] + s_red[2] + s_red[3]) / (float)n);
}

extern "C" void kernel_launch(void* const* d_in, const int* in_sizes, int n_in,
                              void* d_out, int out_size, void* d_ws, size_t ws_size,
                              hipStream_t stream) {
    int n = in_sizes[0];
    const float* beta = (const float*)d_in[1];
    const float* x    = (const float*)d_in[2];
    const int*   pid  = (const int*)d_in[4];
    float* out = (float*)d_out;

    int a_blocks = (n + 255) / 256;                               // 392
    char* ws = (char*)d_ws;
    size_t tab_bytes = (size_t)a_blocks * P_IDS * sizeof(ull);    // ~1.6 MB
    tab_bytes = (tab_bytes + 255) & ~(size_t)255;
    size_t q_bytes = (((size_t)n * 4) + 255) & ~(size_t)255;
    ull*    tables  = (ull*)ws;
    float*  qbuf    = (float*)(ws + tab_bytes);
    char*   p0      = ws + tab_bytes + q_bytes;
    float2* meta    = (float2*)p0;                                // 4 KB
    float*  x_alpha = (float*)(p0 + P_IDS * sizeof(float2));      // 16 KB
    uint4*  gB      = (uint4*)(p0 + P_IDS * sizeof(float2)
                                  + P_IDS * DIM * sizeof(float)); // 16 KB

    stageA_kernel<<<a_blocks, 256, 0, stream>>>(beta, pid, qbuf, tables, n);
    stageB_kernel<<<P_IDS, 64, 0, stream>>>(tables, a_blocks, x, meta, x_alpha, gB, out);
    int loss_blocks = (n + 63) / 64;                              // 1563
    loss_kernel<<<loss_blocks, 256, 0, stream>>>(x, qbuf, pid, meta, x_alpha, gB, out, n);
}

// Round 2
// 89.482 us; speedup vs baseline: 1.1450x; 1.1450x over previous
//
#include <hip/hip_runtime.h>

#define P_IDS 512
#define DIM 8
#define QMIN 0.01f
#define REP 10.0f
#define HITS_B 128               // hits per loss block

typedef unsigned long long ull;
typedef float f32x4 __attribute__((ext_vector_type(4)));
typedef short s16x8 __attribute__((ext_vector_type(8)));

// ---- bf16 helpers (RNE via bit trick) ----
__device__ __forceinline__ unsigned int bf16_rne(float f) {
    unsigned int u = __float_as_uint(f);
    return (u + 0x7FFFu + ((u >> 16) & 1u)) >> 16;   // low 16 bits = bf16
}
__device__ __forceinline__ float bf16_to_f32(unsigned int h) {
    return __uint_as_float(h << 16);
}
// exact-split pack: v[d] ~= hi[d] + lo[d] (both bf16), packed 8x16b -> uint4
__device__ __forceinline__ void split_pack(const float* v, uint4& hiw, uint4& low) {
    unsigned int hb[8], lb[8];
#pragma unroll
    for (int d = 0; d < 8; ++d) {
        unsigned int h = bf16_rne(v[d]);
        float rem = v[d] - bf16_to_f32(h);
        hb[d] = h;
        lb[d] = bf16_rne(rem);
    }
    hiw = make_uint4(hb[0] | (hb[1] << 16), hb[2] | (hb[3] << 16),
                     hb[4] | (hb[5] << 16), hb[6] | (hb[7] << 16));
    low = make_uint4(lb[0] | (lb[1] << 16), lb[2] | (lb[3] << 16),
                     lb[4] | (lb[5] << 16), lb[6] | (lb[7] << 16));
}

// Stage A: q_i = arctanh(beta_i)^2 + QMIN; per-block segmented argmax into LDS
// (key = qbits<<32 | ~i). Table writes are TRANSPOSED (tables[p][block]) so
// stageB reads coalesce; the scatter cost lands on latency-tolerant stores.
__launch_bounds__(256)
__global__ void stageA_kernel(const float* __restrict__ beta,
                              const int* __restrict__ pid,
                              float* __restrict__ q_out,
                              ull* __restrict__ tables, int ts,
                              int n) {
    __shared__ ull s_keys[P_IDS];
    s_keys[threadIdx.x] = 0ULL;
    s_keys[threadIdx.x + 256] = 0ULL;
    __syncthreads();
    int i = blockIdx.x * 256 + threadIdx.x;
    if (i < n) {
        float b = beta[i];
        float at = 0.5f * logf((1.0f + b) / (1.0f - b));   // arctanh
        float qv = fmaf(at, at, QMIN);
        q_out[i] = qv;
        ull key = ((ull)__float_as_uint(qv) << 32) |
                  (ull)(unsigned int)(~(unsigned int)i);
        atomicMax(&s_keys[pid[i]], key);
    }
    __syncthreads();
    tables[(size_t)threadIdx.x * ts + blockIdx.x] = s_keys[threadIdx.x];
    tables[(size_t)(threadIdx.x + 256) * ts + blockIdx.x] = s_keys[threadIdx.x + 256];
}

// Stage B: one block per particle id; 64 threads reduce ntab partial keys
// (now a coalesced contiguous row), decode, gather x_alpha, precompute
// ||x_alpha||^2, emit bf16 hi/lo split for the MFMA loss kernel.
__launch_bounds__(64)
__global__ void stageB_kernel(const ull* __restrict__ tables, int ts, int ntab,
                              const float* __restrict__ x,
                              float2* __restrict__ meta,
                              float* __restrict__ x_alpha,
                              uint4* __restrict__ gB,
                              float* __restrict__ out) {
    int p = blockIdx.x;
    const ull* row = tables + (size_t)p * ts;
    ull k = 0ULL;
    for (int t = threadIdx.x; t < ntab; t += 64) {
        ull v = row[t];
        k = (v > k) ? v : k;
    }
#pragma unroll
    for (int off = 32; off > 0; off >>= 1) {
        ull o = __shfl_down(k, off, 64);
        k = (o > k) ? o : k;
    }
    if (threadIdx.x == 0) {
        bool valid = (k != 0ULL) && (p != 0);
        float qa = valid ? __uint_as_float((unsigned int)(k >> 32)) : 0.0f;
        int idx = valid ? (int)(~(unsigned int)(k & 0xFFFFFFFFull)) : 0;
        float4 a = ((const float4*)x)[idx * 2];
        float4 b = ((const float4*)x)[idx * 2 + 1];
        float xa2 = a.x * a.x;
        xa2 = fmaf(a.y, a.y, xa2); xa2 = fmaf(a.z, a.z, xa2); xa2 = fmaf(a.w, a.w, xa2);
        xa2 = fmaf(b.x, b.x, xa2); xa2 = fmaf(b.y, b.y, xa2); xa2 = fmaf(b.z, b.z, xa2);
        xa2 = fmaf(b.w, b.w, xa2);
        ((float4*)x_alpha)[p * 2] = a;
        ((float4*)x_alpha)[p * 2 + 1] = b;
        meta[p] = make_float2(qa, xa2);
        float xv[8] = {a.x, a.y, a.z, a.w, b.x, b.y, b.z, b.w};
        uint4 hiw, low; split_pack(xv, hiw, low);
        gB[p] = hiw;           // hi half
        gB[P_IDS + p] = low;   // lo half
        if (p == 0) out[0] = 0.0f;
    }
}

// Loss: block = 128 hits x all 512 particles; 4 waves, each wave owns two
// 16-hit row tiles. Per 16-particle column tile: one bv ds_read + one meta
// ds_read feed TWO mfma_f32_16x16x32_bf16, each computing
// sq = ||xi||^2 + ||xa||^2 - 2 xi.xa directly (C seeded with norm sums;
// A = exact bf16 hi/lo split of -2xi packed [hi,lo,hi,lo] over k-groups,
// B = split of xa packed [hi,hi,lo,lo]). A-fragments are loop-invariant.
// Hinge path (dist<1, ~3%/tile) behind a per-tile wave vote. Own-pair
// excluded by pid compare in the rare path; attractive term exact fp32 in
// the prologue. Bounded unroll to keep VGPRs in budget.
__launch_bounds__(256)
__global__ void loss_kernel(const float* __restrict__ x,
                            const float* __restrict__ q,
                            const int* __restrict__ pid,
                            const float2* __restrict__ meta,
                            const float* __restrict__ x_alpha,
                            const uint4* __restrict__ gB,
                            float* __restrict__ out, int n) {
    __shared__ uint4  s_B[2 * P_IDS];      // 16 KB: hi[512] | lo[512]
    __shared__ float2 s_meta[P_IDS];       // 4 KB: (qa, xa2)
    __shared__ uint4  s_A[2 * HITS_B];     // 4 KB: hi[128] | lo[128] of -2x
    __shared__ __align__(16) float s_xi2[HITS_B];
    __shared__ __align__(16) float s_qi[HITS_B];
    __shared__ __align__(16) int   s_pid[HITS_B];

    int tid = threadIdx.x;
    float partial = 0.0f;

    if (tid < HITS_B) {
        int i = blockIdx.x * HITS_B + tid;
        bool act = i < n;
        int ii = act ? i : 0;
        float4 v0 = ((const float4*)x)[ii * 2];
        float4 v1 = ((const float4*)x)[ii * 2 + 1];
        float xv[8] = {v0.x, v0.y, v0.z, v0.w, v1.x, v1.y, v1.z, v1.w};
        float s = 0.0f;
#pragma unroll
        for (int d = 0; d < 8; ++d) s = fmaf(xv[d], xv[d], s);
        float qi = act ? q[ii] : 0.0f;   // qi=0 kills padded rows everywhere
        int   pd = act ? pid[ii] : 0;
        s_xi2[tid] = act ? s : 0.0f;
        s_qi[tid]  = qi;
        s_pid[tid] = pd;
        float m2[8];
#pragma unroll
        for (int d = 0; d < 8; ++d) m2[d] = act ? (-2.0f * xv[d]) : 0.0f;
        uint4 hiw, low; split_pack(m2, hiw, low);
        s_A[tid] = hiw; s_A[HITS_B + tid] = low;
        // attractive own-pair term, exact fp32
        float2 mm = meta[pd];
        float4 a0 = ((const float4*)x_alpha)[pd * 2];
        float4 a1 = ((const float4*)x_alpha)[pd * 2 + 1];
        float dot = xv[0] * a0.x;
        dot = fmaf(xv[1], a0.y, dot); dot = fmaf(xv[2], a0.z, dot);
        dot = fmaf(xv[3], a0.w, dot); dot = fmaf(xv[4], a1.x, dot);
        dot = fmaf(xv[5], a1.y, dot); dot = fmaf(xv[6], a1.z, dot);
        dot = fmaf(xv[7], a1.w, dot);
        float sqe = fmaxf(fmaf(-2.0f, dot, s + mm.y), 0.0f);
        partial = qi * mm.x * sqe;
    }
    for (int k = tid; k < 2 * P_IDS; k += 256) s_B[k] = gB[k];
    for (int k = tid; k < P_IDS; k += 256) s_meta[k] = meta[k];
    __syncthreads();

    int lane = tid & 63;
    int w    = tid >> 6;
    int grp  = lane >> 4;
    int col  = lane & 15;
    int hbase = w * 32;                      // this wave's 32 hits

    // loop-invariant A fragments (k-group sel = grp&1 -> [hi,lo,hi,lo])
    s16x8 av0 = *reinterpret_cast<const s16x8*>(
        &s_A[((grp & 1) ? HITS_B : 0) + hbase + col]);
    s16x8 av1 = *reinterpret_cast<const s16x8*>(
        &s_A[((grp & 1) ? HITS_B : 0) + hbase + 16 + col]);
    // accumulator rows (C map: col=lane&15, row=grp*4+r — m89/round-0 verified)
    int r0 = hbase + (grp << 2);
    int r1 = hbase + 16 + (grp << 2);
    f32x4 xi20 = *reinterpret_cast<const f32x4*>(&s_xi2[r0]);
    f32x4 xi21 = *reinterpret_cast<const f32x4*>(&s_xi2[r1]);
    f32x4 qi0  = *reinterpret_cast<const f32x4*>(&s_qi[r0]);
    f32x4 qi1  = *reinterpret_cast<const f32x4*>(&s_qi[r1]);
    int4  pd0  = *reinterpret_cast<const int4*>(&s_pid[r0]);
    int4  pd1  = *reinterpret_cast<const int4*>(&s_pid[r1]);

    // B base: k-group sel = grp>=2 -> [hi,hi,lo,lo]
    const uint4* bptr = &s_B[((grp >= 2) ? P_IDS : 0) + col];
    f32x4 rp0 = {0.0f, 0.0f, 0.0f, 0.0f};
    f32x4 rp1 = {0.0f, 0.0f, 0.0f, 0.0f};

#pragma unroll 4
    for (int jt = 0; jt < P_IDS / 16; ++jt) {
        s16x8 bv = *reinterpret_cast<const s16x8*>(&bptr[jt * 16]);
        float2 mm = s_meta[jt * 16 + col];
        int p = jt * 16 + col;
        f32x4 c0, c1;
        c0[0] = xi20[0] + mm.y; c0[1] = xi20[1] + mm.y;
        c0[2] = xi20[2] + mm.y; c0[3] = xi20[3] + mm.y;
        c1[0] = xi21[0] + mm.y; c1[1] = xi21[1] + mm.y;
        c1[2] = xi21[2] + mm.y; c1[3] = xi21[3] + mm.y;
        c0 = __builtin_amdgcn_mfma_f32_16x16x32_bf16(av0, bv, c0, 0, 0, 0);
        c1 = __builtin_amdgcn_mfma_f32_16x16x32_bf16(av1, bv, c1, 0, 0, 0);
        float mn0 = fminf(fminf(c0[0], c0[1]), fminf(c0[2], c0[3]));
        if (__any(mn0 < 1.0f)) {
#pragma unroll
            for (int r = 0; r < 4; ++r) {
                float sq = fmaxf(c0[r], 0.0f);
                float vr = fmaxf(1.0f - __builtin_amdgcn_sqrtf(sq), 0.0f);
                float wgt = (pd0.x == p && r == 0) ? 0.0f :
                            (pd0.y == p && r == 1) ? 0.0f :
                            (pd0.z == p && r == 2) ? 0.0f :
                            (pd0.w == p && r == 3) ? 0.0f : mm.x;
                rp0[r] = fmaf(vr, wgt, rp0[r]);
            }
        }
        float mn1 = fminf(fminf(c1[0], c1[1]), fminf(c1[2], c1[3]));
        if (__any(mn1 < 1.0f)) {
#pragma unroll
            for (int r = 0; r < 4; ++r) {
                float sq = fmaxf(c1[r], 0.0f);
                float vr = fmaxf(1.0f - __builtin_amdgcn_sqrtf(sq), 0.0f);
                float wgt = (pd1.x == p && r == 0) ? 0.0f :
                            (pd1.y == p && r == 1) ? 0.0f :
                            (pd1.z == p && r == 2) ? 0.0f :
                            (pd1.w == p && r == 3) ? 0.0f : mm.x;
                rp1[r] = fmaf(vr, wgt, rp1[r]);
            }
        }
    }
    partial += REP * (qi0[0] * rp0[0] + qi0[1] * rp0[1] +
                      qi0[2] * rp0[2] + qi0[3] * rp0[3] +
                      qi1[0] * rp1[0] + qi1[1] * rp1[1] +
                      qi1[2] * rp1[2] + qi1[3] * rp1[3]);

#pragma unroll
    for (int off = 32; off > 0; off >>= 1)
        partial += __shfl_down(partial, off, 64);
    __shared__ float s_red[4];
    if ((tid & 63) == 0) s_red[tid >> 6] = partial;
    __syncthreads();
    if (tid == 0)
        atomicAdd(out, (s_red[0] + s_red[1] + s_red[2] + s_red[3]) / (float)n);
}

extern "C" void kernel_launch(void* const* d_in, const int* in_sizes, int n_in,
                              void* d_out, int out_size, void* d_ws, size_t ws_size,
                              hipStream_t stream) {
    int n = in_sizes[0];
    const float* beta = (const float*)d_in[1];
    const float* x    = (const float*)d_in[2];
    const int*   pid  = (const int*)d_in[4];
    float* out = (float*)d_out;

    int a_blocks = (n + 255) / 256;                               // 392
    int ts = (a_blocks + 7) & ~7;                                 // padded row
    char* ws = (char*)d_ws;
    size_t tab_bytes = (size_t)P_IDS * ts * sizeof(ull);          // ~1.6 MB
    tab_bytes = (tab_bytes + 255) & ~(size_t)255;
    size_t q_bytes = (((size_t)n * 4) + 255) & ~(size_t)255;
    ull*    tables  = (ull*)ws;
    float*  qbuf    = (float*)(ws + tab_bytes);
    char*   p0      = ws + tab_bytes + q_bytes;
    float2* meta    = (float2*)p0;                                // 4 KB
    float*  x_alpha = (float*)(p0 + P_IDS * sizeof(float2));      // 16 KB
    uint4*  gB      = (uint4*)(p0 + P_IDS * sizeof(float2)
                                  + P_IDS * DIM * sizeof(float)); // 16 KB

    stageA_kernel<<<a_blocks, 256, 0, stream>>>(beta, pid, qbuf, tables, ts, n);
    stageB_kernel<<<P_IDS, 64, 0, stream>>>(tables, ts, a_blocks, x, meta, x_alpha, gB, out);
    int loss_blocks = (n + HITS_B - 1) / HITS_B;                  // 782
    loss_kernel<<<loss_blocks, 256, 0, stream>>>(x, qbuf, pid, meta, x_alpha, gB, out, n);
}